// Round 7
// baseline (285.359 us; speedup 1.0000x reference)
//
#include <hip/hip_runtime.h>

// CrossModalAttention2D — collapsed form.
// Attention has a single KV token -> softmax over size-1 axis == 1.0 ->
// ao[b,s,:] = v[b,:] for every s. LayerNorm/Q path is dead.
// out[b,c,h,w] = visual[b,c,h,w] + gamma * (proj_w@(out_w@(Wv@mean(text)+bv)+out_b)+proj_b)[b,c]

#define BB   8
#define CC   1024
#define HWSZ 4096   // H*W
#define NTOK 8

// t[b,c] = mean over NT tokens of text[b, nt, c]
__global__ void cm_mean_kernel(const float* __restrict__ text, float* __restrict__ t) {
    int idx = blockIdx.x * blockDim.x + threadIdx.x;  // BB*CC = 8192
    if (idx >= BB * CC) return;
    int b = idx >> 10;          // / CC
    int c = idx & (CC - 1);     // % CC
    float s = 0.f;
#pragma unroll
    for (int n = 0; n < NTOK; ++n) s += text[(b * NTOK + n) * CC + c];
    t[idx] = s * (1.0f / NTOK);
}

// out[b][c] = sum_j in[b][j] * W[c][j] + bias[c]
// one wave (64 lanes) per output channel c; weight row read once, reused for all 8 batches
__global__ void cm_matvec_kernel(const float* __restrict__ in, const float* __restrict__ W,
                                 const float* __restrict__ bias, float* __restrict__ out) {
    int c    = blockIdx.x;       // 0..CC-1
    int lane = threadIdx.x;      // 0..63
    const float* wrow = W + (size_t)c * CC;
    float acc[BB];
#pragma unroll
    for (int b = 0; b < BB; ++b) acc[b] = 0.f;
    // 256 float4s per weight row / 64 lanes = 4 iterations
#pragma unroll
    for (int it = 0; it < 4; ++it) {
        int j4 = it * 64 + lane;                    // float4 index, 0..255
        float4 wv = ((const float4*)wrow)[j4];
#pragma unroll
        for (int b = 0; b < BB; ++b) {
            float4 iv = ((const float4*)(in + b * CC))[j4];
            acc[b] += iv.x * wv.x + iv.y * wv.y + iv.z * wv.z + iv.w * wv.w;
        }
    }
#pragma unroll
    for (int b = 0; b < BB; ++b) {
        float v = acc[b];
        for (int off = 32; off; off >>= 1) v += __shfl_down(v, off, 64);
        if (lane == 0) out[b * CC + c] = v + bias[c];
    }
}

// out[b,c,hw] = visual[b,c,hw] + gamma * w[b,c]   (float4 over the 4096-contiguous hw dim)
__global__ void cm_add_kernel(const float* __restrict__ visual, const float* __restrict__ w,
                              const float* __restrict__ gamma_p, float* __restrict__ out) {
    const float g = gamma_p[0];
    const size_t N4 = (size_t)BB * CC * HWSZ / 4;   // 8388608
    size_t stride = (size_t)gridDim.x * blockDim.x;
    for (size_t i = (size_t)blockIdx.x * blockDim.x + threadIdx.x; i < N4; i += stride) {
        float4 v = ((const float4*)visual)[i];
        int bc = (int)(i >> 10);                    // 1024 float4s per (b,c)
        float a = g * w[bc];
        v.x += a; v.y += a; v.z += a; v.w += a;
        ((float4*)out)[i] = v;
    }
}

extern "C" void kernel_launch(void* const* d_in, const int* in_sizes, int n_in,
                              void* d_out, int out_size, void* d_ws, size_t ws_size,
                              hipStream_t stream) {
    const float* visual    = (const float*)d_in[0];
    const float* text      = (const float*)d_in[1];
    const float* in_proj_w = (const float*)d_in[2];
    const float* in_proj_b = (const float*)d_in[3];
    const float* out_w     = (const float*)d_in[4];
    const float* out_b     = (const float*)d_in[5];
    // d_in[6] ln_w, d_in[7] ln_b — dead (softmax over size-1 axis)
    const float* proj_w    = (const float*)d_in[8];
    const float* proj_b    = (const float*)d_in[9];
    const float* gamma     = (const float*)d_in[10];
    float* out = (float*)d_out;

    float* ws = (float*)d_ws;            // needs 4 * 8192 floats = 128 KB
    float* t  = ws;
    float* v  = ws + BB * CC;
    float* u  = ws + 2 * BB * CC;
    float* wf = ws + 3 * BB * CC;

    cm_mean_kernel<<<(BB * CC + 255) / 256, 256, 0, stream>>>(text, t);
    cm_matvec_kernel<<<CC, 64, 0, stream>>>(t, in_proj_w + 2 * CC * CC, in_proj_b + 2 * CC, v);
    cm_matvec_kernel<<<CC, 64, 0, stream>>>(v, out_w, out_b, u);
    cm_matvec_kernel<<<CC, 64, 0, stream>>>(u, proj_w, proj_b, wf);
    cm_add_kernel<<<2048, 256, 0, stream>>>(visual, wf, gamma, out);
}

// Round 12
// 270.816 us; speedup vs baseline: 1.0537x; 1.0537x over previous
//
#include <hip/hip_runtime.h>

// CrossModalAttention2D — collapsed form.
// Attention has a single KV token -> softmax over size-1 axis == 1.0 ->
// ao[b,s,:] = v[b,:] for every s. LayerNorm/Q path is dead.
// out[b,c,h,w] = visual[b,c,h,w] + gamma * (proj_w@(out_w@(Wv@mean(text)+bv)+out_b)+proj_b)[b,c]

#define BB   8
#define CC   1024
#define HWSZ 4096   // H*W
#define NTOK 8

// t[b,c] = mean over NT tokens of text[b, nt, c]
__global__ void cm_mean_kernel(const float* __restrict__ text, float* __restrict__ t) {
    int idx = blockIdx.x * blockDim.x + threadIdx.x;  // BB*CC = 8192
    if (idx >= BB * CC) return;
    int b = idx >> 10;          // / CC
    int c = idx & (CC - 1);     // % CC
    float s = 0.f;
#pragma unroll
    for (int n = 0; n < NTOK; ++n) s += text[(b * NTOK + n) * CC + c];
    t[idx] = s * (1.0f / NTOK);
}

// out[b][c] = sum_j in[b][j] * W[c][j] + bias[c]
// one block (4 waves) per output channel c; wave q handles batches 2q,2q+1.
// Weight row (4 KB) shared across the 4 waves via L1; inputs (32 KB) L2-hot.
__global__ void cm_matvec_kernel(const float* __restrict__ in, const float* __restrict__ W,
                                 const float* __restrict__ bias, float* __restrict__ out) {
    int c    = blockIdx.x;            // 0..CC-1
    int wave = threadIdx.x >> 6;      // 0..3
    int lane = threadIdx.x & 63;
    int b0 = wave * 2, b1 = b0 + 1;
    const float4* wrow = (const float4*)(W + (size_t)c * CC);
    const float4* in0  = (const float4*)(in + b0 * CC);
    const float4* in1  = (const float4*)(in + b1 * CC);
    float acc0 = 0.f, acc1 = 0.f;
#pragma unroll
    for (int it = 0; it < 4; ++it) {
        int j4 = it * 64 + lane;      // float4 index, 0..255
        float4 wv = wrow[j4];
        float4 i0 = in0[j4];
        float4 i1 = in1[j4];
        acc0 += i0.x * wv.x + i0.y * wv.y + i0.z * wv.z + i0.w * wv.w;
        acc1 += i1.x * wv.x + i1.y * wv.y + i1.z * wv.z + i1.w * wv.w;
    }
#pragma unroll
    for (int off = 32; off; off >>= 1) {
        acc0 += __shfl_down(acc0, off, 64);
        acc1 += __shfl_down(acc1, off, 64);
    }
    if (lane == 0) {
        float bc = bias[c];
        out[b0 * CC + c] = acc0 + bc;
        out[b1 * CC + c] = acc1 + bc;
    }
}

// out[b,c,:] = visual[b,c,:] + gamma * w[b,c]
// m13-proven streaming pattern: one block per (b,c) row (1024 float4s),
// 256 threads x 4 independent float4 load/store pairs, consecutive addresses.
// w[bc] is wave-uniform -> one scalar load per block.
__global__ void cm_add_kernel(const float* __restrict__ visual, const float* __restrict__ w,
                              const float* __restrict__ gamma_p, float* __restrict__ out) {
    const int bc = blockIdx.x;                         // 0..8191
    const float a = gamma_p[0] * w[bc];
    const float4* vin  = (const float4*)visual + (size_t)bc * (HWSZ / 4);
    float4*       vout = (float4*)out          + (size_t)bc * (HWSZ / 4);
    const int t = threadIdx.x;                         // 0..255
#pragma unroll
    for (int k = 0; k < 4; ++k) {
        float4 v = vin[t + k * 256];
        v.x += a; v.y += a; v.z += a; v.w += a;
        vout[t + k * 256] = v;
    }
}

extern "C" void kernel_launch(void* const* d_in, const int* in_sizes, int n_in,
                              void* d_out, int out_size, void* d_ws, size_t ws_size,
                              hipStream_t stream) {
    const float* visual    = (const float*)d_in[0];
    const float* text      = (const float*)d_in[1];
    const float* in_proj_w = (const float*)d_in[2];
    const float* in_proj_b = (const float*)d_in[3];
    const float* out_w     = (const float*)d_in[4];
    const float* out_b     = (const float*)d_in[5];
    // d_in[6] ln_w, d_in[7] ln_b — dead (softmax over size-1 axis)
    const float* proj_w    = (const float*)d_in[8];
    const float* proj_b    = (const float*)d_in[9];
    const float* gamma     = (const float*)d_in[10];
    float* out = (float*)d_out;

    float* ws = (float*)d_ws;            // needs 4 * 8192 floats = 128 KB
    float* t  = ws;
    float* v  = ws + BB * CC;
    float* u  = ws + 2 * BB * CC;
    float* wf = ws + 3 * BB * CC;

    cm_mean_kernel<<<(BB * CC + 255) / 256, 256, 0, stream>>>(text, t);
    cm_matvec_kernel<<<CC, 256, 0, stream>>>(t, in_proj_w + 2 * CC * CC, in_proj_b + 2 * CC, v);
    cm_matvec_kernel<<<CC, 256, 0, stream>>>(v, out_w, out_b, u);
    cm_matvec_kernel<<<CC, 256, 0, stream>>>(u, proj_w, proj_b, wf);
    cm_add_kernel<<<BB * CC, 256, 0, stream>>>(visual, wf, gamma, out);
}